// Round 4
// baseline (341.693 us; speedup 1.0000x reference)
//
#include <hip/hip_runtime.h>
#include <stdint.h>

// ---------------------------------------------------------------------------
// SelfAttention: q,k,v = hs@W.T+b ; E = exp(q@k.T) (no max-sub needed: |logit|<~60)
// l = rowsum(E); context = (E@Vt)*(1/l); scores_j = sum_q E[q,j]/l_q
// R14: fix R13's two regressions.
//   (1) context split-K atomics: 16.8M f32 atomicAdds -> WRITE_SIZE 66MB,
//       MfmaUtil 15.8, 81.8us. REVERTED to non-split (128 blocks, NT=32,
//       plain stores, no zero pass). Half-machine but zero overhead.
//   (2) core tile-end vmcnt(0) drain had only ~2 phases of cover for B(t+1)
//       (staged in phase 1). Now ALL 8 loads of t+1 issue in phase 0 ->
//       ~3 phases (~600-700cyc) issue-to-wait distance, covers L2-hit lat.
//   Core: m201 geometry: BM=BN=256, 8 waves 2Mx4N, per-wave 128x64,
//   acc[8][4], 4 phases x 16 MFMA per K-tile (0.375 ds_read/MFMA), 2-slot
//   ring 128KB, setprio+lgkmcnt(0)+sched_barrier per phase, verified
//   conflict-free 8-chunk XOR swizzle. Grids: proj 384, logits 256 (1 pass),
//   context 128.
// ws layout: q[0..16M) k[16..32M) vt[32..48M) l@48M(32K) part@48M+128K(1MB)
//   {hsb[49..65M) Wb[65..71M)} | E[49..81M) aliased.  Requires ws >= 81MB.
// ---------------------------------------------------------------------------

typedef __attribute__((ext_vector_type(8))) short short8;
typedef __attribute__((ext_vector_type(4))) float floatx4;
typedef __attribute__((ext_vector_type(4))) unsigned short ushort4v;
typedef unsigned short u16;

__device__ __forceinline__ u16 f2bf(float f) {
  union { float f; uint32_t u; } v; v.f = f;
  uint32_t u = v.u;
  return (u16)((u + 0x7FFFu + ((u >> 16) & 1u)) >> 16);  // RNE
}
__device__ __forceinline__ float bf2f(u16 h) {
  union { uint32_t u; float f; } v; v.u = ((uint32_t)h) << 16; return v.f;
}

#define AS3(p) ((__attribute__((address_space(3))) void*)(uint32_t)(uintptr_t)(p))
#define AS1(p) ((__attribute__((address_space(1))) void*)(uintptr_t)(p))

// ---------------------------------------------------------------------------
// Fused convert: hs (8192 blocks) + Wq/Wk/Wv (3*1024 blocks); block 0 also
// zeroes lsum (needed by logits' atomics).
__global__ __launch_bounds__(256) void cvt_all_kernel(
    const float* __restrict__ hs, const float* __restrict__ Wq,
    const float* __restrict__ Wk, const float* __restrict__ Wv,
    u16* __restrict__ hsb, u16* __restrict__ Wb, float* __restrict__ lsum) {
  const int bx = blockIdx.x;
  const float* src;
  u16* dst;
  int i;
  if (bx < 8192) {
    i = bx * 1024 + threadIdx.x * 4;
    src = hs; dst = hsb;
  } else {
    const int idx = bx - 8192;
    const int p = idx >> 10, blk = idx & 1023;
    src = (p == 0) ? Wq : (p == 1) ? Wk : Wv;
    dst = Wb + p * 1048576;
    i = blk * 1024 + threadIdx.x * 4;
  }
  const float4 v = *(const float4*)(src + i);
  ushort4v o;
  o[0] = f2bf(v.x); o[1] = f2bf(v.y); o[2] = f2bf(v.z); o[3] = f2bf(v.w);
  *(ushort4v*)(dst + i) = o;
  if (bx == 0) {
    float4 z = {0.f, 0.f, 0.f, 0.f};
#pragma unroll
    for (int k = 0; k < 8; ++k)
      *(float4*)(lsum + threadIdx.x * 32 + k * 4) = z;
  }
}

// ---------------------------------------------------------------------------
// m201-geometry bt-GEMM core: C[256,256] += A[256,K] * B[256,K]^T
// 512 thr / 8 waves (2Mx4N), per-wave 128x64 = acc[8][4] frags of 16x16.
// K-tile 64. LDS slot: A 256x64 (32KB) + B 256x64 (32KB); 2-slot ring 128KB.
// Per K-tile/wave: 24 ds_read_b128, 64 MFMA over 4 phases of 16.
// Staging: ALL 8 t+1 loads issue in phase 0; single drain at phase-3 end
// (~3 phases of cover). Swizzle: LDS chunk (row,kc) holds global chunk
// kc^(row&7); ds_read at chunk ((ks*4+quad)^(fr&7)) — conflict-free.
#define DC_SLOTU 32768  // u16 per ring slot (A 16384 + B 16384)

template <int NT>
__device__ __forceinline__ void deep_core256(const u16* __restrict__ A,
                                             const u16* __restrict__ B,
                                             int lda, int ldb,
                                             u16* smem, floatx4 acc[8][4]) {
  const int tid  = threadIdx.x;
  const int lane = tid & 63;
  const int w    = tid >> 6;
  const int wm   = w >> 2;            // 0..1  (M half, 128 rows)
  const int wn   = w & 3;             // 0..3  (N quarter, 64 cols)
  const int fr   = lane & 15;
  const int quad = lane >> 4;
  const int pc0  = (quad ^ (fr & 7)) * 8;
  const int pc1  = ((4 + quad) ^ (fr & 7)) * 8;

  const u16* pA[4]; const u16* pB[4];
  uint32_t dA[4], dB[4];
#pragma unroll
  for (int j = 0; j < 4; ++j) {
    const int c = tid + j * 512, row = c >> 3, kc = c & 7;
    pA[j] = A + row * lda + (kc ^ (row & 7)) * 8;
    pB[j] = B + row * ldb + (kc ^ (row & 7)) * 8;
    dA[j] = c * 8;
    dB[j] = 16384 + c * 8;
  }

  // prologue: stage tile 0 into slot 0, drain, sync
#pragma unroll
  for (int j = 0; j < 4; ++j)
    __builtin_amdgcn_global_load_lds(AS1(pA[j]), AS3(smem + dA[j]), 16, 0, 0);
#pragma unroll
  for (int j = 0; j < 4; ++j)
    __builtin_amdgcn_global_load_lds(AS1(pB[j]), AS3(smem + dB[j]), 16, 0, 0);
#pragma unroll
  for (int j = 0; j < 4; ++j) { pA[j] += 64; pB[j] += 64; }
  asm volatile("s_waitcnt vmcnt(0)" ::: "memory");
  __builtin_amdgcn_s_barrier();

  const int arow = wm * 128 + fr;   // + ah*64 + mi*16
  const int brow = wn * 64 + fr;    // + ni*16
  uint32_t dst = DC_SLOTU;          // stage slot for tile t+1

#pragma unroll 2
  for (int t = 0; t < NT; ++t) {
    const u16* sA = smem + (t & 1) * DC_SLOTU;
    const u16* sB = sA + 16384;
    const bool more = (t < NT - 1);
    short8 af[4], bf[4];

    // ---- phase 0: A(ah0,ks0)+B(ks0); stage ALL of t+1; MFMA acc[0..3]
#pragma unroll
    for (int mi = 0; mi < 4; ++mi)
      af[mi] = *(const short8*)(sA + (arow + mi * 16) * 64 + pc0);
#pragma unroll
    for (int ni = 0; ni < 4; ++ni)
      bf[ni] = *(const short8*)(sB + (brow + ni * 16) * 64 + pc0);
    if (more) {
#pragma unroll
      for (int j = 0; j < 4; ++j) {
        __builtin_amdgcn_global_load_lds(AS1(pA[j]), AS3(smem + dst + dA[j]), 16, 0, 0);
        pA[j] += 64;
      }
#pragma unroll
      for (int j = 0; j < 4; ++j) {
        __builtin_amdgcn_global_load_lds(AS1(pB[j]), AS3(smem + dst + dB[j]), 16, 0, 0);
        pB[j] += 64;
      }
    }
    __builtin_amdgcn_s_barrier();
    asm volatile("s_waitcnt lgkmcnt(0)" ::: "memory");
    __builtin_amdgcn_sched_barrier(0);
    __builtin_amdgcn_s_setprio(1);
#pragma unroll
    for (int mi = 0; mi < 4; ++mi)
#pragma unroll
      for (int ni = 0; ni < 4; ++ni)
        acc[mi][ni] = __builtin_amdgcn_mfma_f32_16x16x32_bf16(af[mi], bf[ni],
                                                              acc[mi][ni], 0, 0, 0);
    __builtin_amdgcn_s_setprio(0);
    __builtin_amdgcn_s_barrier();

    // ---- phase 1: A(ah1,ks0) (reuse bf); MFMA acc[4..7]
#pragma unroll
    for (int mi = 0; mi < 4; ++mi)
      af[mi] = *(const short8*)(sA + (arow + 64 + mi * 16) * 64 + pc0);
    __builtin_amdgcn_s_barrier();
    asm volatile("s_waitcnt lgkmcnt(0)" ::: "memory");
    __builtin_amdgcn_sched_barrier(0);
    __builtin_amdgcn_s_setprio(1);
#pragma unroll
    for (int mi = 0; mi < 4; ++mi)
#pragma unroll
      for (int ni = 0; ni < 4; ++ni)
        acc[mi + 4][ni] = __builtin_amdgcn_mfma_f32_16x16x32_bf16(af[mi], bf[ni],
                                                                  acc[mi + 4][ni], 0, 0, 0);
    __builtin_amdgcn_s_setprio(0);
    __builtin_amdgcn_s_barrier();

    // ---- phase 2: A(ah0,ks1)+B(ks1); MFMA acc[0..3]
#pragma unroll
    for (int mi = 0; mi < 4; ++mi)
      af[mi] = *(const short8*)(sA + (arow + mi * 16) * 64 + pc1);
#pragma unroll
    for (int ni = 0; ni < 4; ++ni)
      bf[ni] = *(const short8*)(sB + (brow + ni * 16) * 64 + pc1);
    __builtin_amdgcn_s_barrier();
    asm volatile("s_waitcnt lgkmcnt(0)" ::: "memory");
    __builtin_amdgcn_sched_barrier(0);
    __builtin_amdgcn_s_setprio(1);
#pragma unroll
    for (int mi = 0; mi < 4; ++mi)
#pragma unroll
      for (int ni = 0; ni < 4; ++ni)
        acc[mi][ni] = __builtin_amdgcn_mfma_f32_16x16x32_bf16(af[mi], bf[ni],
                                                              acc[mi][ni], 0, 0, 0);
    __builtin_amdgcn_s_setprio(0);
    __builtin_amdgcn_s_barrier();

    // ---- phase 3: A(ah1,ks1); MFMA acc[4..7]; drain t+1 (issued ph0); flip
#pragma unroll
    for (int mi = 0; mi < 4; ++mi)
      af[mi] = *(const short8*)(sA + (arow + 64 + mi * 16) * 64 + pc1);
    __builtin_amdgcn_s_barrier();
    asm volatile("s_waitcnt lgkmcnt(0)" ::: "memory");
    __builtin_amdgcn_sched_barrier(0);
    __builtin_amdgcn_s_setprio(1);
#pragma unroll
    for (int mi = 0; mi < 4; ++mi)
#pragma unroll
      for (int ni = 0; ni < 4; ++ni)
        acc[mi + 4][ni] = __builtin_amdgcn_mfma_f32_16x16x32_bf16(af[mi], bf[ni],
                                                                  acc[mi + 4][ni], 0, 0, 0);
    __builtin_amdgcn_s_setprio(0);
    asm volatile("s_waitcnt vmcnt(0)" ::: "memory");
    __builtin_amdgcn_s_barrier();
    dst ^= DC_SLOTU;
  }
}

// ---------------------------------------------------------------------------
// K1: q/k/v projections.  C = hs @ W.T + b.  p=0:q  p=1:k  p=2: v transposed.
// grid (4,32,3) = 384 blocks (1.5 passes of 256).
__global__ __launch_bounds__(512, 2) void proj_deep_kernel(
    const u16* __restrict__ hsb, const u16* __restrict__ Wb,
    const float* __restrict__ bq, const float* __restrict__ bk,
    const float* __restrict__ bv,
    u16* __restrict__ qo, u16* __restrict__ ko, u16* __restrict__ vt) {
  extern __shared__ __align__(16) u16 smem[];
  floatx4 acc[8][4];
#pragma unroll
  for (int i = 0; i < 8; ++i)
#pragma unroll
    for (int j = 0; j < 4; ++j) acc[i][j] = {0.f, 0.f, 0.f, 0.f};

  const int p    = blockIdx.z;
  const int flat = blockIdx.x + blockIdx.y * 4;       // 0..127 per p
  const int swz  = (flat & 7) * 16 + (flat >> 3);     // bijective XCD chunk
  const int m0   = (swz >> 2) * 256;
  const int n0   = (swz & 3) * 256;

  deep_core256<16>(hsb + m0 * 1024, Wb + p * 1048576 + n0 * 1024,
                   1024, 1024, smem, acc);

  const float* bias = (p == 0) ? bq : (p == 1) ? bk : bv;
  const int lane = threadIdx.x & 63, w = threadIdx.x >> 6;
  const int wm = w >> 2, wn = w & 3;
  const int fr = lane & 15, rg4 = (lane >> 4) * 4;

  if (p < 2) {
    u16* out = (p == 0) ? qo : ko;
#pragma unroll
    for (int ai = 0; ai < 8; ++ai) {
      const int mb = m0 + wm * 128 + (ai >> 2) * 64 + (ai & 3) * 16 + rg4;
#pragma unroll
      for (int ni = 0; ni < 4; ++ni) {
        const int n = n0 + wn * 64 + ni * 16 + fr;
        const float bn = bias[n];
#pragma unroll
        for (int r = 0; r < 4; ++r)
          out[(mb + r) * 1024 + n] = f2bf(acc[ai][ni][r] + bn);
      }
    }
  } else {
    // v transposed: vt[b][h][s], 4 consecutive s per lane -> 8B packed store
#pragma unroll
    for (int ai = 0; ai < 8; ++ai) {
      const int mbase = m0 + wm * 128 + (ai >> 2) * 64 + (ai & 3) * 16 + rg4;
      const int b = mbase >> 11, s = mbase & 2047;
#pragma unroll
      for (int ni = 0; ni < 4; ++ni) {
        const int n = n0 + wn * 64 + ni * 16 + fr;
        const float bn = bias[n];
        ushort4v pk;
#pragma unroll
        for (int r = 0; r < 4; ++r) pk[r] = f2bf(acc[ai][ni][r] + bn);
        *(ushort4v*)(vt + b * 2097152 + n * 2048 + s) = pk;
      }
    }
  }
}

// ---------------------------------------------------------------------------
// K2: E = exp(q @ k.T) (bf16), l = rowsum(E) via 16-lane shfl + atomics.
// grid (8,8,4) = 256 blocks = 1 perfect pass.
__global__ __launch_bounds__(512, 2) void logits_deep_kernel(
    const u16* __restrict__ q, const u16* __restrict__ k,
    u16* __restrict__ E, float* __restrict__ lsum) {
  extern __shared__ __align__(16) u16 smem[];
  floatx4 acc[8][4];
#pragma unroll
  for (int i = 0; i < 8; ++i)
#pragma unroll
    for (int j = 0; j < 4; ++j) acc[i][j] = {0.f, 0.f, 0.f, 0.f};

  const int flat = blockIdx.x + blockIdx.y * 8 + blockIdx.z * 64;  // 0..255
  const int swz  = (flat & 7) * 32 + (flat >> 3);
  const int b    = swz >> 6;
  const int m0   = ((swz >> 3) & 7) * 256;   // query tile base
  const int n0   = (swz & 7) * 256;          // key tile base

  deep_core256<16>(q + (b * 2048 + m0) * 1024, k + (b * 2048 + n0) * 1024,
                   1024, 1024, smem, acc);

  const int lane = threadIdx.x & 63, w = threadIdx.x >> 6;
  const int wm = w >> 2, wn = w & 3;
  const int fr = lane & 15, quad = lane >> 4;
  u16* Eb = E + b * 4194304;
  float* lb = lsum + b * 2048;

#pragma unroll
  for (int ai = 0; ai < 8; ++ai) {
    floatx4 rs = {0.f, 0.f, 0.f, 0.f};
    const int rbase = m0 + wm * 128 + (ai >> 2) * 64 + (ai & 3) * 16 + quad * 4;
#pragma unroll
    for (int ni = 0; ni < 4; ++ni) {
      const int n = n0 + wn * 64 + ni * 16 + fr;
#pragma unroll
      for (int r = 0; r < 4; ++r) {
        const float e = __expf(acc[ai][ni][r]);
        rs[r] += e;
        Eb[(rbase + r) * 2048 + n] = f2bf(e);
      }
    }
#pragma unroll
    for (int off = 1; off < 16; off <<= 1) {
      rs[0] += __shfl_xor(rs[0], off, 64);
      rs[1] += __shfl_xor(rs[1], off, 64);
      rs[2] += __shfl_xor(rs[2], off, 64);
      rs[3] += __shfl_xor(rs[3], off, 64);
    }
    if (fr == 0) {
#pragma unroll
      for (int r = 0; r < 4; ++r) atomicAdd(&lb[rbase + r], rs[r]);
    }
  }
}

// ---------------------------------------------------------------------------
// K4: context = (E @ Vt) * (1/l) -> d_out fp32.  Non-split: grid (4,8,4) =
// 128 blocks (half machine, but zero extra traffic / no atomics).
__global__ __launch_bounds__(512, 2) void context_deep_kernel(
    const u16* __restrict__ E, const u16* __restrict__ vt,
    const float* __restrict__ lsum, float* __restrict__ out) {
  extern __shared__ __align__(16) u16 smem[];
  floatx4 acc[8][4];
#pragma unroll
  for (int i = 0; i < 8; ++i)
#pragma unroll
    for (int j = 0; j < 4; ++j) acc[i][j] = {0.f, 0.f, 0.f, 0.f};

  const int flat = blockIdx.x + blockIdx.y * 4 + blockIdx.z * 32;  // 0..127
  const int swz  = (flat & 7) * 16 + (flat >> 3);
  const int b    = swz >> 5;
  const int m0   = ((swz >> 2) & 7) * 256;   // query tile
  const int n0   = (swz & 3) * 256;          // h tile

  deep_core256<32>(E + b * 4194304 + m0 * 2048, vt + b * 2097152 + n0 * 2048,
                   2048, 2048, smem, acc);

  const int lane = threadIdx.x & 63, w = threadIdx.x >> 6;
  const int wm = w >> 2, wn = w & 3;
  const int fr = lane & 15, rg4 = (lane >> 4) * 4;
  const float* lb = lsum + b * 2048;

#pragma unroll
  for (int ai = 0; ai < 8; ++ai) {
    const int rbase = m0 + wm * 128 + (ai >> 2) * 64 + (ai & 3) * 16 + rg4;
    float rinv[4];
#pragma unroll
    for (int r = 0; r < 4; ++r) rinv[r] = 1.0f / lb[rbase + r];
#pragma unroll
    for (int ni = 0; ni < 4; ++ni) {
      const int n = n0 + wn * 64 + ni * 16 + fr;
#pragma unroll
      for (int r = 0; r < 4; ++r)
        out[(b * 2048 + rbase + r) * 1024 + n] = acc[ai][ni][r] * rinv[r];
    }
  }
}

// ---------------------------------------------------------------------------
// K3a: partial column sums: part[b][g][j] = sum_{q in rows g*64..+64} E[q,j]/l_q
// grid (4,32,2) = 256 blocks (z splits the j range).
__global__ __launch_bounds__(256) void colsum_part_kernel(
    const u16* __restrict__ E, const float* __restrict__ lsum,
    float* __restrict__ part) {
  const int b  = blockIdx.x;
  const int g  = blockIdx.y;
  const int q0 = g * 64;
  const int j  = blockIdx.z * 1024 + threadIdx.x * 4;
  const u16* Eb = E + b * 4194304;
  const float* lb = lsum + b * 2048;
  float acc[4];
#pragma unroll
  for (int c = 0; c < 4; ++c) acc[c] = 0.f;
  for (int r = 0; r < 64; ++r) {
    const int qi = q0 + r;
    const float rinv = 1.0f / lb[qi];
    const ushort4v ev = *(const ushort4v*)(Eb + qi * 2048 + j);
#pragma unroll
    for (int c = 0; c < 4; ++c) acc[c] += bf2f((u16)ev[c]) * rinv;
  }
  float4 o = {acc[0], acc[1], acc[2], acc[3]};
  *(float4*)(part + (b * 32 + g) * 2048 + j) = o;
}

// K3b: scores[b][j] = sum_g part[b][g][j]
__global__ __launch_bounds__(256) void colsum_reduce_kernel(
    const float* __restrict__ part, float* __restrict__ scores) {
  const int b = blockIdx.x;
  const int j = blockIdx.y * 256 + threadIdx.x;
  const float* pb = part + b * 32 * 2048 + j;
  float s = 0.f;
#pragma unroll
  for (int g = 0; g < 32; ++g) s += pb[g * 2048];
  scores[b * 2048 + j] = s;
}

// ---------------------------------------------------------------------------
extern "C" void kernel_launch(void* const* d_in, const int* in_sizes, int n_in,
                              void* d_out, int out_size, void* d_ws, size_t ws_size,
                              hipStream_t stream) {
  const float* hs = (const float*)d_in[0];
  const float* Wq = (const float*)d_in[1];
  const float* bq = (const float*)d_in[2];
  const float* Wk = (const float*)d_in[3];
  const float* bk = (const float*)d_in[4];
  const float* Wv = (const float*)d_in[5];
  const float* bv = (const float*)d_in[6];

  char* ws = (char*)d_ws;
  u16*   qw  = (u16*)(ws);                                // 16 MB
  u16*   kw  = (u16*)(ws + (16u << 20));                  // 16 MB
  u16*   vtw = (u16*)(ws + (32u << 20));                  // 16 MB
  float* lw  = (float*)(ws + (48u << 20));                // 32 KB
  float* pw  = (float*)(ws + (48u << 20) + (128u << 10)); // 1 MB partials
  u16*   hsb = (u16*)(ws + (49u << 20));                  // 16 MB (dead after proj)
  u16*   Wb  = (u16*)(ws + (65u << 20));                  // 6 MB  (dead after proj)
  u16*   Ew  = (u16*)(ws + (49u << 20));                  // 32 MB (aliases hsb/Wb)

  float* outc = (float*)d_out;           // context [4,2048,1024]
  float* outs = outc + 8388608;          // scores  [4,2048]

  static int s_attr_done = 0;
  if (!s_attr_done) {
    (void)hipFuncSetAttribute((const void*)proj_deep_kernel,
                              hipFuncAttributeMaxDynamicSharedMemorySize, 131072);
    (void)hipFuncSetAttribute((const void*)logits_deep_kernel,
                              hipFuncAttributeMaxDynamicSharedMemorySize, 131072);
    (void)hipFuncSetAttribute((const void*)context_deep_kernel,
                              hipFuncAttributeMaxDynamicSharedMemorySize, 131072);
    s_attr_done = 1;
  }

  cvt_all_kernel<<<11264, 256, 0, stream>>>(hs, Wq, Wk, Wv, hsb, Wb, lw);
  proj_deep_kernel<<<dim3(4, 32, 3), 512, 131072, stream>>>(hsb, Wb, bq, bk, bv, qw, kw, vtw);
  logits_deep_kernel<<<dim3(8, 8, 4), 512, 131072, stream>>>(qw, kw, Ew, lw);
  context_deep_kernel<<<dim3(4, 8, 4), 512, 131072, stream>>>(Ew, vtw, lw, outc);
  colsum_part_kernel<<<dim3(4, 32, 2), 256, 0, stream>>>(Ew, lw, pw);
  colsum_reduce_kernel<<<dim3(4, 8), 256, 0, stream>>>(pw, outs);
}

// Round 5
// 255.208 us; speedup vs baseline: 1.3389x; 1.3389x over previous
//
#include <hip/hip_runtime.h>
#include <stdint.h>

// ---------------------------------------------------------------------------
// SelfAttention: q,k,v = hs@W.T+b ; E = exp(q@k.T) (no max-sub needed: |logit|<~60)
// l = rowsum(E); context = (E@Vt)*(1/l); scores_j = sum_q E[q,j]/l_q
// R15: R12 pipeline restored + merged-phase core + faster cvt.
//   Evidence: R12 (3-slot ring, counted vmcnt(6)) proj=62us MfmaUtil 33;
//   R13/R14 (2-slot, vmcnt(0) drain/tile) proj=105us MfmaUtil 19. The drain
//   was the regression (m218: counted-vmcnt IS the 8-phase gain). Geometry
//   reverts to R12's 64x64/wave; the one new variable: ONE barrier pair per
//   K-tile around 32 MFMA (was 2 pairs around 16) — in-tile phase barriers
//   are not correctness-bearing (WAR on stage slot protected by end-of-tile
//   barrier one tile earlier + per-wave lgkmcnt before its MFMAs).
//   cvt: 8 floats/thread (2x float4 -> bf16x8 16B store).
// ws layout: q[0..16M) k[16..32M) vt[32..48M) l@48M(32K) part@48M+128K(1MB)
//   {hsb[49..65M) Wb[65..71M)} | E[49..81M) aliased.  Requires ws >= 81MB.
// ---------------------------------------------------------------------------

typedef __attribute__((ext_vector_type(8))) short short8;
typedef __attribute__((ext_vector_type(4))) float floatx4;
typedef __attribute__((ext_vector_type(4))) unsigned short ushort4v;
typedef __attribute__((ext_vector_type(8))) unsigned short ushort8v;
typedef unsigned short u16;

__device__ __forceinline__ u16 f2bf(float f) {
  union { float f; uint32_t u; } v; v.f = f;
  uint32_t u = v.u;
  return (u16)((u + 0x7FFFu + ((u >> 16) & 1u)) >> 16);  // RNE
}
__device__ __forceinline__ float bf2f(u16 h) {
  union { uint32_t u; float f; } v; v.u = ((uint32_t)h) << 16; return v.f;
}

#define AS3(p) ((__attribute__((address_space(3))) void*)(uint32_t)(uintptr_t)(p))
#define AS1(p) ((__attribute__((address_space(1))) void*)(uintptr_t)(p))

// ---------------------------------------------------------------------------
// Fused convert: hs (4096 blocks) + Wq/Wk/Wv (3*512 blocks), 8 floats/thread.
// block 0 also zeroes lsum (needed by logits' atomics).
__global__ __launch_bounds__(256) void cvt_all_kernel(
    const float* __restrict__ hs, const float* __restrict__ Wq,
    const float* __restrict__ Wk, const float* __restrict__ Wv,
    u16* __restrict__ hsb, u16* __restrict__ Wb, float* __restrict__ lsum) {
  const int bx = blockIdx.x;
  const float* src;
  u16* dst;
  int i;
  if (bx < 4096) {
    i = bx * 2048 + threadIdx.x * 8;
    src = hs; dst = hsb;
  } else {
    const int idx = bx - 4096;
    const int p = idx >> 9, blk = idx & 511;
    src = (p == 0) ? Wq : (p == 1) ? Wk : Wv;
    dst = Wb + p * 1048576;
    i = blk * 2048 + threadIdx.x * 8;
  }
  const float4 v0 = *(const float4*)(src + i);
  const float4 v1 = *(const float4*)(src + i + 4);
  ushort8v o;
  o[0] = f2bf(v0.x); o[1] = f2bf(v0.y); o[2] = f2bf(v0.z); o[3] = f2bf(v0.w);
  o[4] = f2bf(v1.x); o[5] = f2bf(v1.y); o[6] = f2bf(v1.z); o[7] = f2bf(v1.w);
  *(ushort8v*)(dst + i) = o;
  if (bx == 0) {
    float4 z = {0.f, 0.f, 0.f, 0.f};
#pragma unroll
    for (int k = 0; k < 8; ++k)
      *(float4*)(lsum + threadIdx.x * 32 + k * 4) = z;
  }
}

// ---------------------------------------------------------------------------
// Deep-pipelined bt-GEMM core: C[256,128] += A[256,K] * B[128,K]^T
// 512 thr / 8 waves (4Mx2N), per-wave 64x64 = acc[4][4].  K-tile 64.
// LDS slot: A 256x64 (32KB) + B 128x64 (16KB) = 24576 u16; 3-slot ring 144KB.
// Per K-tile: 6 global_load_lds/thread, 16 ds_read_b128/thread, 32 MFMA,
// ONE barrier pair.  Stage t+2 during t; counted vmcnt(6) (never 0 in loop).
// Swizzle: LDS chunk (row,kc) holds global chunk kc^(row&7) (16B chunks);
// ds_read at chunk ((ks*4+quad)^(fr&7)) — conflict-free (R6/R12-verified).
#define DC_SLOTU 24576

template <int NT>
__device__ __forceinline__ void deep_core(const u16* __restrict__ A,
                                          const u16* __restrict__ B,
                                          int lda, int ldb,
                                          u16* smem, floatx4 acc[4][4]) {
  const int tid  = threadIdx.x;
  const int lane = tid & 63;
  const int w    = tid >> 6;
  const int wr   = (w >> 1) * 64;      // wave row base (m), 0..192
  const int wc   = (w & 1) * 64;       // wave col base (n), 0..64
  const int fr   = lane & 15;
  const int quad = lane >> 4;
  const int pc0  = (quad ^ (fr & 7)) * 8;
  const int pc1  = ((4 + quad) ^ (fr & 7)) * 8;

  const u16* pA[4]; uint32_t dA[4];
#pragma unroll
  for (int j = 0; j < 4; ++j) {
    const int c = tid + j * 512, row = c >> 3, kc = c & 7;
    pA[j] = A + row * lda + (kc ^ (row & 7)) * 8;
    dA[j] = c * 8;
  }
  const u16* pB[2]; uint32_t dB[2];
#pragma unroll
  for (int j = 0; j < 2; ++j) {
    const int c = tid + j * 512, row = c >> 3, kc = c & 7;
    pB[j] = B + row * ldb + (kc ^ (row & 7)) * 8;
    dB[j] = 16384 + c * 8;
  }

#define DC_STAGE(off) do { u16* s_ = smem + (off);                                      \
    _Pragma("unroll") for (int j_ = 0; j_ < 4; ++j_) {                                   \
      __builtin_amdgcn_global_load_lds(AS1(pA[j_]), AS3(s_ + dA[j_]), 16, 0, 0);        \
      pA[j_] += 64; }                                                                    \
    _Pragma("unroll") for (int j_ = 0; j_ < 2; ++j_) {                                   \
      __builtin_amdgcn_global_load_lds(AS1(pB[j_]), AS3(s_ + dB[j_]), 16, 0, 0);        \
      pB[j_] += 64; }                                                                    \
  } while (0)

  // prologue: stage tiles 0,1 (12 loads); wait tile 0 (oldest 6) landed
  DC_STAGE(0);
  DC_STAGE(DC_SLOTU);
  asm volatile("s_waitcnt vmcnt(6)" ::: "memory");
  __builtin_amdgcn_s_barrier();

  uint32_t cur = 0, nxt = DC_SLOTU, prv = 2 * DC_SLOTU;

#pragma unroll
  for (int t = 0; t < NT; ++t) {
    const u16* sA = smem + cur;
    const u16* sB = sA + 16384;
    short8 a0[4], b0[4], a1[4], b1[4];

    // 16 ds_read_b128: both k-slices of this tile
#pragma unroll
    for (int i = 0; i < 4; ++i) {
      a0[i] = *(const short8*)(sA + (wr + i * 16 + fr) * 64 + pc0);
      b0[i] = *(const short8*)(sB + (wc + i * 16 + fr) * 64 + pc0);
      a1[i] = *(const short8*)(sA + (wr + i * 16 + fr) * 64 + pc1);
      b1[i] = *(const short8*)(sB + (wc + i * 16 + fr) * 64 + pc1);
    }

    // stage t+2 into the slot tile t-1 used; counted wait: t+1 landed
    if (t < NT - 2) {
      DC_STAGE(prv);
      asm volatile("s_waitcnt vmcnt(6)" ::: "memory");
    } else if (t == NT - 2) {
      asm volatile("s_waitcnt vmcnt(0)" ::: "memory");  // tail drain only
    }
    __builtin_amdgcn_s_barrier();
    asm volatile("s_waitcnt lgkmcnt(0)" ::: "memory");
    __builtin_amdgcn_sched_barrier(0);
    __builtin_amdgcn_s_setprio(1);
#pragma unroll
    for (int mi = 0; mi < 4; ++mi)
#pragma unroll
      for (int ni = 0; ni < 4; ++ni)
        acc[mi][ni] = __builtin_amdgcn_mfma_f32_16x16x32_bf16(a0[mi], b0[ni],
                                                              acc[mi][ni], 0, 0, 0);
#pragma unroll
    for (int mi = 0; mi < 4; ++mi)
#pragma unroll
      for (int ni = 0; ni < 4; ++ni)
        acc[mi][ni] = __builtin_amdgcn_mfma_f32_16x16x32_bf16(a1[mi], b1[ni],
                                                              acc[mi][ni], 0, 0, 0);
    __builtin_amdgcn_s_setprio(0);
    __builtin_amdgcn_s_barrier();

    const uint32_t tmp = cur; cur = nxt; nxt = prv; prv = tmp;
  }
#undef DC_STAGE
}

// ---------------------------------------------------------------------------
// K1: q/k/v projections.  C = hs @ W.T + b.  p=0:q  p=1:k  p=2: v transposed.
// grid (8,32,3) = 768 blocks.
__global__ __launch_bounds__(512, 2) void proj_deep_kernel(
    const u16* __restrict__ hsb, const u16* __restrict__ Wb,
    const float* __restrict__ bq, const float* __restrict__ bk,
    const float* __restrict__ bv,
    u16* __restrict__ qo, u16* __restrict__ ko, u16* __restrict__ vt) {
  extern __shared__ __align__(16) u16 smem[];
  floatx4 acc[4][4];
#pragma unroll
  for (int i = 0; i < 4; ++i)
#pragma unroll
    for (int j = 0; j < 4; ++j) acc[i][j] = {0.f, 0.f, 0.f, 0.f};

  const int p    = blockIdx.z;
  const int flat = blockIdx.x + blockIdx.y * 8;       // 0..255 per p
  const int swz  = (flat & 7) * 32 + (flat >> 3);     // bijective XCD chunk
  const int m0   = (swz >> 3) * 256;
  const int n0   = (swz & 7) * 128;

  deep_core<16>(hsb + m0 * 1024, Wb + p * 1048576 + n0 * 1024,
                1024, 1024, smem, acc);

  const float* bias = (p == 0) ? bq : (p == 1) ? bk : bv;
  const int lane = threadIdx.x & 63, w = threadIdx.x >> 6;
  const int wm = w >> 1, wn = w & 1;
  const int fr = lane & 15, rg4 = (lane >> 4) * 4;

  if (p < 2) {
    u16* out = (p == 0) ? qo : ko;
#pragma unroll
    for (int mi = 0; mi < 4; ++mi)
#pragma unroll
      for (int ni = 0; ni < 4; ++ni) {
        const int n = n0 + wn * 64 + ni * 16 + fr;
        const float bn = bias[n];
#pragma unroll
        for (int r = 0; r < 4; ++r) {
          const int m = m0 + wm * 64 + mi * 16 + rg4 + r;
          out[m * 1024 + n] = f2bf(acc[mi][ni][r] + bn);
        }
      }
  } else {
    // v transposed: vt[b][h][s], 4 consecutive s per lane -> 8B packed store
#pragma unroll
    for (int mi = 0; mi < 4; ++mi) {
      const int mbase = m0 + wm * 64 + mi * 16 + rg4;
      const int b = mbase >> 11, s = mbase & 2047;
#pragma unroll
      for (int ni = 0; ni < 4; ++ni) {
        const int n = n0 + wn * 64 + ni * 16 + fr;
        const float bn = bias[n];
        ushort4v pk;
#pragma unroll
        for (int r = 0; r < 4; ++r) pk[r] = f2bf(acc[mi][ni][r] + bn);
        *(ushort4v*)(vt + b * 2097152 + n * 2048 + s) = pk;
      }
    }
  }
}

// ---------------------------------------------------------------------------
// K2: E = exp(q @ k.T) (bf16), l = rowsum(E) via 16-lane shfl + atomics.
// grid (16,8,4) = 512 blocks = 2 perfect passes.
__global__ __launch_bounds__(512, 2) void logits_deep_kernel(
    const u16* __restrict__ q, const u16* __restrict__ k,
    u16* __restrict__ E, float* __restrict__ lsum) {
  extern __shared__ __align__(16) u16 smem[];
  floatx4 acc[4][4];
#pragma unroll
  for (int i = 0; i < 4; ++i)
#pragma unroll
    for (int j = 0; j < 4; ++j) acc[i][j] = {0.f, 0.f, 0.f, 0.f};

  const int flat = blockIdx.x + blockIdx.y * 16 + blockIdx.z * 128;  // 0..511
  const int swz  = (flat & 7) * 64 + (flat >> 3);
  const int b    = swz >> 7;
  const int m0   = ((swz >> 4) & 7) * 256;   // query tile base
  const int n0   = (swz & 15) * 128;         // key tile base

  deep_core<16>(q + (b * 2048 + m0) * 1024, k + (b * 2048 + n0) * 1024,
                1024, 1024, smem, acc);

  const int lane = threadIdx.x & 63, w = threadIdx.x >> 6;
  const int wm = w >> 1, wn = w & 1;
  const int fr = lane & 15, quad = lane >> 4;
  u16* Eb = E + b * 4194304;
  float* lb = lsum + b * 2048;

#pragma unroll
  for (int mi = 0; mi < 4; ++mi) {
    floatx4 rs = {0.f, 0.f, 0.f, 0.f};
    const int rbase = m0 + wm * 64 + mi * 16 + quad * 4;
#pragma unroll
    for (int ni = 0; ni < 4; ++ni) {
      const int n = n0 + wn * 64 + ni * 16 + fr;
#pragma unroll
      for (int r = 0; r < 4; ++r) {
        const float e = __expf(acc[mi][ni][r]);
        rs[r] += e;
        Eb[(rbase + r) * 2048 + n] = f2bf(e);
      }
    }
#pragma unroll
    for (int off = 1; off < 16; off <<= 1) {
      rs[0] += __shfl_xor(rs[0], off, 64);
      rs[1] += __shfl_xor(rs[1], off, 64);
      rs[2] += __shfl_xor(rs[2], off, 64);
      rs[3] += __shfl_xor(rs[3], off, 64);
    }
    if (fr == 0) {
#pragma unroll
      for (int r = 0; r < 4; ++r) atomicAdd(&lb[rbase + r], rs[r]);
    }
  }
}

// ---------------------------------------------------------------------------
// K4: context = (E @ Vt) * (1/l) -> d_out fp32. grid (8,8,4) = 256 = 1 pass.
__global__ __launch_bounds__(512, 2) void context_deep_kernel(
    const u16* __restrict__ E, const u16* __restrict__ vt,
    const float* __restrict__ lsum, float* __restrict__ out) {
  extern __shared__ __align__(16) u16 smem[];
  floatx4 acc[4][4];
#pragma unroll
  for (int i = 0; i < 4; ++i)
#pragma unroll
    for (int j = 0; j < 4; ++j) acc[i][j] = {0.f, 0.f, 0.f, 0.f};

  const int flat = blockIdx.x + blockIdx.y * 8 + blockIdx.z * 64;  // 0..255
  const int swz  = (flat & 7) * 32 + (flat >> 3);
  const int b    = swz >> 6;
  const int m0   = ((swz >> 3) & 7) * 256;   // query tile
  const int n0   = (swz & 7) * 128;          // h tile

  deep_core<32>(E + b * 4194304 + m0 * 2048, vt + b * 2097152 + n0 * 2048,
                2048, 2048, smem, acc);

  const int lane = threadIdx.x & 63, w = threadIdx.x >> 6;
  const int wm = w >> 1, wn = w & 1;
  const int fr = lane & 15, rg4 = (lane >> 4) * 4;
  const float* lb = lsum + b * 2048;

#pragma unroll
  for (int mi = 0; mi < 4; ++mi) {
    const int rbase = m0 + wm * 64 + mi * 16 + rg4;
    float rinv[4];
#pragma unroll
    for (int r = 0; r < 4; ++r) rinv[r] = 1.0f / lb[rbase + r];
#pragma unroll
    for (int ni = 0; ni < 4; ++ni) {
      const int n = n0 + wn * 64 + ni * 16 + fr;
#pragma unroll
      for (int r = 0; r < 4; ++r)
        out[(b * 2048 + rbase + r) * 1024 + n] = acc[mi][ni][r] * rinv[r];
    }
  }
}

// ---------------------------------------------------------------------------
// K3a: partial column sums: part[b][g][j] = sum_{q in rows g*64..+64} E[q,j]/l_q
// grid (4,32,2) = 256 blocks (z splits the j range).
__global__ __launch_bounds__(256) void colsum_part_kernel(
    const u16* __restrict__ E, const float* __restrict__ lsum,
    float* __restrict__ part) {
  const int b  = blockIdx.x;
  const int g  = blockIdx.y;
  const int q0 = g * 64;
  const int j  = blockIdx.z * 1024 + threadIdx.x * 4;
  const u16* Eb = E + b * 4194304;
  const float* lb = lsum + b * 2048;
  float acc[4];
#pragma unroll
  for (int c = 0; c < 4; ++c) acc[c] = 0.f;
  for (int r = 0; r < 64; ++r) {
    const int qi = q0 + r;
    const float rinv = 1.0f / lb[qi];
    const ushort4v ev = *(const ushort4v*)(Eb + qi * 2048 + j);
#pragma unroll
    for (int c = 0; c < 4; ++c) acc[c] += bf2f((u16)ev[c]) * rinv;
  }
  float4 o = {acc[0], acc[1], acc[2], acc[3]};
  *(float4*)(part + (b * 32 + g) * 2048 + j) = o;
}

// K3b: scores[b][j] = sum_g part[b][g][j]
__global__ __launch_bounds__(256) void colsum_reduce_kernel(
    const float* __restrict__ part, float* __restrict__ scores) {
  const int b = blockIdx.x;
  const int j = blockIdx.y * 256 + threadIdx.x;
  const float* pb = part + b * 32 * 2048 + j;
  float s = 0.f;
#pragma unroll
  for (int g = 0; g < 32; ++g) s += pb[g * 2048];
  scores[b * 2048 + j] = s;
}

// ---------------------------------------------------------------------------
extern "C" void kernel_launch(void* const* d_in, const int* in_sizes, int n_in,
                              void* d_out, int out_size, void* d_ws, size_t ws_size,
                              hipStream_t stream) {
  const float* hs = (const float*)d_in[0];
  const float* Wq = (const float*)d_in[1];
  const float* bq = (const float*)d_in[2];
  const float* Wk = (const float*)d_in[3];
  const float* bk = (const float*)d_in[4];
  const float* Wv = (const float*)d_in[5];
  const float* bv = (const float*)d_in[6];

  char* ws = (char*)d_ws;
  u16*   qw  = (u16*)(ws);                                // 16 MB
  u16*   kw  = (u16*)(ws + (16u << 20));                  // 16 MB
  u16*   vtw = (u16*)(ws + (32u << 20));                  // 16 MB
  float* lw  = (float*)(ws + (48u << 20));                // 32 KB
  float* pw  = (float*)(ws + (48u << 20) + (128u << 10)); // 1 MB partials
  u16*   hsb = (u16*)(ws + (49u << 20));                  // 16 MB (dead after proj)
  u16*   Wb  = (u16*)(ws + (65u << 20));                  // 6 MB  (dead after proj)
  u16*   Ew  = (u16*)(ws + (49u << 20));                  // 32 MB (aliases hsb/Wb)

  float* outc = (float*)d_out;           // context [4,2048,1024]
  float* outs = outc + 8388608;          // scores  [4,2048]

  static int s_attr_done = 0;
  if (!s_attr_done) {
    (void)hipFuncSetAttribute((const void*)proj_deep_kernel,
                              hipFuncAttributeMaxDynamicSharedMemorySize, 147456);
    (void)hipFuncSetAttribute((const void*)logits_deep_kernel,
                              hipFuncAttributeMaxDynamicSharedMemorySize, 147456);
    (void)hipFuncSetAttribute((const void*)context_deep_kernel,
                              hipFuncAttributeMaxDynamicSharedMemorySize, 147456);
    s_attr_done = 1;
  }

  cvt_all_kernel<<<5632, 256, 0, stream>>>(hs, Wq, Wk, Wv, hsb, Wb, lw);
  proj_deep_kernel<<<dim3(8, 32, 3), 512, 147456, stream>>>(hsb, Wb, bq, bk, bv, qw, kw, vtw);
  logits_deep_kernel<<<dim3(16, 8, 4), 512, 147456, stream>>>(qw, kw, Ew, lw);
  context_deep_kernel<<<dim3(8, 8, 4), 512, 147456, stream>>>(Ew, vtw, lw, outc);
  colsum_part_kernel<<<dim3(4, 32, 2), 256, 0, stream>>>(Ew, lw, pw);
  colsum_reduce_kernel<<<dim3(4, 8), 256, 0, stream>>>(pw, outs);
}

// Round 6
// 235.849 us; speedup vs baseline: 1.4488x; 1.0821x over previous
//
#include <hip/hip_runtime.h>
#include <stdint.h>

// ---------------------------------------------------------------------------
// SelfAttention: q,k,v = hs@W.T+b ; E = exp(q@k.T) (no max-sub needed: |logit|<~60)
// l = rowsum(E); context = (E@Vt)*(1/l); scores_j = sum_q E[q,j]/l_q
// R16: hedged experiment.
//   proj/context/colsum = R12 VERBATIM (verified 241us total; proj 62us).
//   logits = NEW quadrant 4-phase 256x256 core (m201-faithful ledger):
//     8 waves 2Mx4N of 128x64, phases = C-quadrants Q00,Q01,Q10,Q11
//     (16 MFMA each; 12/4/12/4 ds_reads), stage 1 half-tile (2 loads) per
//     phase in order A0,B0,B1,A1 of t+1, vmcnt(4) in p0/p1/p3 BEFORE the
//     leading barrier (per-wave counter + barrier = cross-wave guarantee),
//     never drains to 0 in the loop (tail peeled: vmcnt(2)/(0)).
//   cvt = R15's 8-float/thread version.
// ws layout: q[0..16M) k[16..32M) vt[32..48M) l@48M(32K) part@48M+128K(1MB)
//   {hsb[49..65M) Wb[65..71M)} | E[49..81M) aliased.  Requires ws >= 81MB.
// ---------------------------------------------------------------------------

typedef __attribute__((ext_vector_type(8))) short short8;
typedef __attribute__((ext_vector_type(4))) float floatx4;
typedef __attribute__((ext_vector_type(4))) unsigned short ushort4v;
typedef __attribute__((ext_vector_type(8))) unsigned short ushort8v;
typedef unsigned short u16;

__device__ __forceinline__ u16 f2bf(float f) {
  union { float f; uint32_t u; } v; v.f = f;
  uint32_t u = v.u;
  return (u16)((u + 0x7FFFu + ((u >> 16) & 1u)) >> 16);  // RNE
}
__device__ __forceinline__ float bf2f(u16 h) {
  union { uint32_t u; float f; } v; v.u = ((uint32_t)h) << 16; return v.f;
}

#define AS3(p) ((__attribute__((address_space(3))) void*)(uint32_t)(uintptr_t)(p))
#define AS1(p) ((__attribute__((address_space(1))) void*)(uintptr_t)(p))

// ---------------------------------------------------------------------------
// Fused convert: hs (4096 blocks) + Wq/Wk/Wv (3*512 blocks), 8 floats/thread.
// block 0 also zeroes lsum (needed by logits' atomics).
__global__ __launch_bounds__(256) void cvt_all_kernel(
    const float* __restrict__ hs, const float* __restrict__ Wq,
    const float* __restrict__ Wk, const float* __restrict__ Wv,
    u16* __restrict__ hsb, u16* __restrict__ Wb, float* __restrict__ lsum) {
  const int bx = blockIdx.x;
  const float* src;
  u16* dst;
  int i;
  if (bx < 4096) {
    i = bx * 2048 + threadIdx.x * 8;
    src = hs; dst = hsb;
  } else {
    const int idx = bx - 4096;
    const int p = idx >> 9, blk = idx & 511;
    src = (p == 0) ? Wq : (p == 1) ? Wk : Wv;
    dst = Wb + p * 1048576;
    i = blk * 2048 + threadIdx.x * 8;
  }
  const float4 v0 = *(const float4*)(src + i);
  const float4 v1 = *(const float4*)(src + i + 4);
  ushort8v o;
  o[0] = f2bf(v0.x); o[1] = f2bf(v0.y); o[2] = f2bf(v0.z); o[3] = f2bf(v0.w);
  o[4] = f2bf(v1.x); o[5] = f2bf(v1.y); o[6] = f2bf(v1.z); o[7] = f2bf(v1.w);
  *(ushort8v*)(dst + i) = o;
  if (bx == 0) {
    float4 z = {0.f, 0.f, 0.f, 0.f};
#pragma unroll
    for (int k = 0; k < 8; ++k)
      *(float4*)(lsum + threadIdx.x * 32 + k * 4) = z;
  }
}

// ---------------------------------------------------------------------------
// R12-verbatim deep core: C[256,128] += A[256,K] * B[128,K]^T
// 512 thr / 8 waves (4Mx2N), 64x64/wave. 3-slot ring (144KB), stage t+2
// during t, counted vmcnt(6), 2 fine phases x 16 MFMA. Conflict-free XOR.
#define DC_SLOTU 24576

template <int NT>
__device__ __forceinline__ void deep_core(const u16* __restrict__ A,
                                          const u16* __restrict__ B,
                                          int lda, int ldb,
                                          u16* smem, floatx4 acc[4][4]) {
  const int tid  = threadIdx.x;
  const int lane = tid & 63;
  const int w    = tid >> 6;
  const int wm   = w >> 1;
  const int wn   = w & 1;
  const int fr   = lane & 15;
  const int quad = lane >> 4;
  const int pc0  = (quad ^ (fr & 7)) * 8;
  const int pc1  = ((4 + quad) ^ (fr & 7)) * 8;

  const u16* pA[4]; uint32_t dA[4];
#pragma unroll
  for (int j = 0; j < 4; ++j) {
    const int c = tid + j * 512, row = c >> 3, kc = c & 7;
    pA[j] = A + row * lda + (kc ^ (row & 7)) * 8;
    dA[j] = c * 8;
  }
  const u16* pB[2]; uint32_t dB[2];
#pragma unroll
  for (int j = 0; j < 2; ++j) {
    const int c = tid + j * 512, row = c >> 3, kc = c & 7;
    pB[j] = B + row * ldb + (kc ^ (row & 7)) * 8;
    dB[j] = 16384 + c * 8;
  }

#define DC_STA(u) do { u16* s_ = smem + ((u) % 3) * DC_SLOTU;                                  \
    _Pragma("unroll") for (int j_ = 0; j_ < 4; ++j_)                                           \
      __builtin_amdgcn_global_load_lds(AS1(pA[j_] + (u) * 64), AS3(s_ + dA[j_]), 16, 0, 0);   \
  } while (0)
#define DC_STB(u) do { u16* s_ = smem + ((u) % 3) * DC_SLOTU;                                  \
    _Pragma("unroll") for (int j_ = 0; j_ < 2; ++j_)                                           \
      __builtin_amdgcn_global_load_lds(AS1(pB[j_] + (u) * 64), AS3(s_ + dB[j_]), 16, 0, 0);   \
  } while (0)

  DC_STA(0); DC_STB(0); DC_STA(1); DC_STB(1);
  asm volatile("s_waitcnt vmcnt(6)" ::: "memory");
  __builtin_amdgcn_s_barrier();

  const int arow0 = wm * 64 + fr;
  const int brow0 = wn * 64 + fr;

#pragma unroll
  for (int t = 0; t < NT; ++t) {
    const u16* sA = smem + (t % 3) * DC_SLOTU;
    const u16* sB = sA + 16384;
    short8 af[4], bf[4];

    // ---- phase 0 (ks=0): 8 ds_read; stage A(t+2); 16 MFMA
#pragma unroll
    for (int mi = 0; mi < 4; ++mi)
      af[mi] = *(const short8*)(sA + (arow0 + mi * 16) * 64 + pc0);
#pragma unroll
    for (int ni = 0; ni < 4; ++ni)
      bf[ni] = *(const short8*)(sB + (brow0 + ni * 16) * 64 + pc0);
    if (t < NT - 2) DC_STA(t + 2);
    __builtin_amdgcn_s_barrier();
    asm volatile("s_waitcnt lgkmcnt(0)" ::: "memory");
    __builtin_amdgcn_sched_barrier(0);
    __builtin_amdgcn_s_setprio(1);
#pragma unroll
    for (int mi = 0; mi < 4; ++mi)
#pragma unroll
      for (int ni = 0; ni < 4; ++ni)
        acc[mi][ni] = __builtin_amdgcn_mfma_f32_16x16x32_bf16(af[mi], bf[ni],
                                                              acc[mi][ni], 0, 0, 0);
    __builtin_amdgcn_s_setprio(0);
    __builtin_amdgcn_s_barrier();

    // ---- phase 1 (ks=1): 8 ds_read; stage B(t+2); counted vmcnt(6); 16 MFMA
#pragma unroll
    for (int mi = 0; mi < 4; ++mi)
      af[mi] = *(const short8*)(sA + (arow0 + mi * 16) * 64 + pc1);
#pragma unroll
    for (int ni = 0; ni < 4; ++ni)
      bf[ni] = *(const short8*)(sB + (brow0 + ni * 16) * 64 + pc1);
    if (t < NT - 2) {
      DC_STB(t + 2);
      asm volatile("s_waitcnt vmcnt(6)" ::: "memory");
    } else if (t == NT - 2) {
      asm volatile("s_waitcnt vmcnt(0)" ::: "memory");  // tail drain only
    }
    __builtin_amdgcn_s_barrier();
    asm volatile("s_waitcnt lgkmcnt(0)" ::: "memory");
    __builtin_amdgcn_sched_barrier(0);
    __builtin_amdgcn_s_setprio(1);
#pragma unroll
    for (int mi = 0; mi < 4; ++mi)
#pragma unroll
      for (int ni = 0; ni < 4; ++ni)
        acc[mi][ni] = __builtin_amdgcn_mfma_f32_16x16x32_bf16(af[mi], bf[ni],
                                                              acc[mi][ni], 0, 0, 0);
    __builtin_amdgcn_s_setprio(0);
    __builtin_amdgcn_s_barrier();
  }
#undef DC_STA
#undef DC_STB
}

// ---------------------------------------------------------------------------
// K1: q/k/v projections (R12 verbatim). grid (8,32,3) = 768 blocks.
__global__ __launch_bounds__(512, 2) void proj_deep_kernel(
    const u16* __restrict__ hsb, const u16* __restrict__ Wb,
    const float* __restrict__ bq, const float* __restrict__ bk,
    const float* __restrict__ bv,
    u16* __restrict__ qo, u16* __restrict__ ko, u16* __restrict__ vt) {
  extern __shared__ __align__(16) u16 smem[];
  floatx4 acc[4][4];
#pragma unroll
  for (int i = 0; i < 4; ++i)
#pragma unroll
    for (int j = 0; j < 4; ++j) acc[i][j] = {0.f, 0.f, 0.f, 0.f};

  const int p    = blockIdx.z;
  const int flat = blockIdx.x + blockIdx.y * 8;
  const int swz  = (flat & 7) * 32 + (flat >> 3);
  const int m0   = (swz >> 3) * 256;
  const int n0   = (swz & 7) * 128;

  deep_core<16>(hsb + m0 * 1024, Wb + p * 1048576 + n0 * 1024, 1024, 1024, smem, acc);

  const float* bias = (p == 0) ? bq : (p == 1) ? bk : bv;
  const int lane = threadIdx.x & 63, w = threadIdx.x >> 6;
  const int wm = w >> 1, wn = w & 1;
  const int fr = lane & 15, rg4 = (lane >> 4) * 4;

  if (p < 2) {
    u16* out = (p == 0) ? qo : ko;
#pragma unroll
    for (int mi = 0; mi < 4; ++mi)
#pragma unroll
      for (int ni = 0; ni < 4; ++ni) {
        const int n = n0 + wn * 64 + ni * 16 + fr;
        const float bn = bias[n];
#pragma unroll
        for (int r = 0; r < 4; ++r) {
          const int m = m0 + wm * 64 + mi * 16 + rg4 + r;
          out[m * 1024 + n] = f2bf(acc[mi][ni][r] + bn);
        }
      }
  } else {
#pragma unroll
    for (int mi = 0; mi < 4; ++mi) {
      const int mbase = m0 + wm * 64 + mi * 16 + rg4;
      const int b = mbase >> 11, s = mbase & 2047;
#pragma unroll
      for (int ni = 0; ni < 4; ++ni) {
        const int n = n0 + wn * 64 + ni * 16 + fr;
        const float bn = bias[n];
        ushort4v pk;
#pragma unroll
        for (int r = 0; r < 4; ++r) pk[r] = f2bf(acc[mi][ni][r] + bn);
        *(ushort4v*)(vt + b * 2097152 + n * 2048 + s) = pk;
      }
    }
  }
}

// ---------------------------------------------------------------------------
// K2 (R16 NEW): quadrant 4-phase 256x256 deep core for E = exp(q@k.T).
// grid (8,8,4) = 256 blocks = 1 perfect pass. 2-slot LDS (2x64KB), per tile:
// phases Q00,Q01,Q10,Q11 (16 MFMA each), stage halves A0,B0,B1,A1 of t+1,
// vmcnt(4) in p0/p1/p3 before the leading barrier; tail peeled.
__global__ __launch_bounds__(512, 2) void logits_q4_kernel(
    const u16* __restrict__ q, const u16* __restrict__ k,
    u16* __restrict__ E, float* __restrict__ lsum) {
  extern __shared__ __align__(16) u16 smem[];  // 2 x 32768 u16
  const int tid  = threadIdx.x;
  const int lane = tid & 63;
  const int w    = tid >> 6;
  const int wr4  = w >> 2;        // 0..1: M half base (x64 within half)
  const int wc4  = w & 3;         // 0..3: N 32-col lane within half
  const int fr   = lane & 15;
  const int kq   = lane >> 4;
  const int pc0  = (kq ^ (fr & 7)) * 8;
  const int pc1  = ((4 + kq) ^ (fr & 7)) * 8;

  const int flat = blockIdx.x + blockIdx.y * 8 + blockIdx.z * 64;  // 0..255
  const int swz  = (flat & 7) * 32 + (flat >> 3);
  const int b    = swz >> 6;
  const int m0   = ((swz >> 3) & 7) * 256;
  const int n0   = (swz & 7) * 256;

  const u16* Ag = q + (b * 2048 + m0) * 1024;
  const u16* Bg = k + (b * 2048 + n0) * 1024;

  // staging: half = 128 rows x 64 k (16KB) = 2 loads/thread.
  const u16* pAs[2]; const u16* pBs[2]; uint32_t dof[2];
#pragma unroll
  for (int j = 0; j < 2; ++j) {
    const int c = tid + j * 512, rl = c >> 3, kc = c & 7;
    const int gc = (kc ^ (rl & 7)) * 8;
    pAs[j] = Ag + rl * 1024 + gc;
    pBs[j] = Bg + rl * 1024 + gc;
    dof[j] = c * 8;
  }
#define ST_A(h, tt, sbase) do { _Pragma("unroll") for (int j_ = 0; j_ < 2; ++j_)      \
    __builtin_amdgcn_global_load_lds(AS1(pAs[j_] + (h) * 131072 + (tt) * 64),         \
        AS3(smem + (sbase) + (h) * 8192 + dof[j_]), 16, 0, 0); } while (0)
#define ST_B(h, tt, sbase) do { _Pragma("unroll") for (int j_ = 0; j_ < 2; ++j_)      \
    __builtin_amdgcn_global_load_lds(AS1(pBs[j_] + (h) * 131072 + (tt) * 64),         \
        AS3(smem + (sbase) + 16384 + (h) * 8192 + dof[j_]), 16, 0, 0); } while (0)

  floatx4 acc[2][2][4][2];
#pragma unroll
  for (int i = 0; i < 2; ++i)
#pragma unroll
    for (int j = 0; j < 2; ++j)
#pragma unroll
      for (int mi = 0; mi < 4; ++mi)
#pragma unroll
        for (int ni = 0; ni < 2; ++ni) acc[i][j][mi][ni] = {0.f, 0.f, 0.f, 0.f};

  // prologue: tile 0 halves in ledger order A0,B0,B1,A1; wait A0,B0.
  ST_A(0, 0, 0); ST_B(0, 0, 0); ST_B(1, 0, 0); ST_A(1, 0, 0);
  asm volatile("s_waitcnt vmcnt(4)" ::: "memory");
  __builtin_amdgcn_s_barrier();

  const int ar0 = wr4 * 64 + fr;       // A row base, + ah*128 + mi*16
  const int br0 = wc4 * 32 + fr;       // B row base, + bh*128 + ni*16
  short8 af[4][2], bf[2][2];

#define Q4_READ_A(ah) do { _Pragma("unroll") for (int mi = 0; mi < 4; ++mi) {          \
    af[mi][0] = *(const short8*)(sA + ((ah) * 128 + ar0 + mi * 16) * 64 + pc0);        \
    af[mi][1] = *(const short8*)(sA + ((ah) * 128 + ar0 + mi * 16) * 64 + pc1); } } while (0)
#define Q4_READ_B(bh) do { _Pragma("unroll") for (int ni = 0; ni < 2; ++ni) {          \
    bf[ni][0] = *(const short8*)(sB + ((bh) * 128 + br0 + ni * 16) * 64 + pc0);        \
    bf[ni][1] = *(const short8*)(sB + ((bh) * 128 + br0 + ni * 16) * 64 + pc1); } } while (0)
#define Q4_MFMA(ah, bh) do {                                                           \
    __builtin_amdgcn_s_barrier();                                                      \
    asm volatile("s_waitcnt lgkmcnt(0)" ::: "memory");                                 \
    __builtin_amdgcn_sched_barrier(0);                                                 \
    __builtin_amdgcn_s_setprio(1);                                                     \
    _Pragma("unroll") for (int mi = 0; mi < 4; ++mi)                                   \
      _Pragma("unroll") for (int ni = 0; ni < 2; ++ni)                                 \
        _Pragma("unroll") for (int ks = 0; ks < 2; ++ks)                               \
          acc[ah][bh][mi][ni] = __builtin_amdgcn_mfma_f32_16x16x32_bf16(               \
              af[mi][ks], bf[ni][ks], acc[ah][bh][mi][ni], 0, 0, 0);                   \
    __builtin_amdgcn_s_setprio(0);                                                     \
    __builtin_amdgcn_s_barrier(); } while (0)

  for (int t = 0; t < 15; ++t) {
    const uint32_t sb = (uint32_t)(t & 1) * 32768u;
    const uint32_t sn = (uint32_t)((t + 1) & 1) * 32768u;
    const u16* sA = smem + sb;
    const u16* sB = sA + 16384;

    // p0: Q00 — reads A(ah0)+B(bh0); stage A0(t+1); vmcnt(4) [guards p1's B1]
    Q4_READ_A(0); Q4_READ_B(0);
    ST_A(0, t + 1, sn);
    asm volatile("s_waitcnt vmcnt(4)" ::: "memory");
    Q4_MFMA(0, 0);
    // p1: Q01 — reads B(bh1); stage B0(t+1); vmcnt(4) [guards p2's A1]
    Q4_READ_B(1);
    ST_B(0, t + 1, sn);
    asm volatile("s_waitcnt vmcnt(4)" ::: "memory");
    Q4_MFMA(0, 1);
    // p2: Q10 — reads A(ah1)+B(bh0); stage B1(t+1); no vmcnt
    Q4_READ_A(1); Q4_READ_B(0);
    ST_B(1, t + 1, sn);
    Q4_MFMA(1, 0);
    // p3: Q11 — reads B(bh1); stage A1(t+1); vmcnt(4) [guards next p0]
    Q4_READ_B(1);
    ST_A(1, t + 1, sn);
    asm volatile("s_waitcnt vmcnt(4)" ::: "memory");
    Q4_MFMA(1, 1);
  }

  { // tail t = 15 (slot 1), no staging; counted drains 2 -> 0
    const u16* sA = smem + 32768;
    const u16* sB = sA + 16384;
    Q4_READ_A(0); Q4_READ_B(0);
    asm volatile("s_waitcnt vmcnt(2)" ::: "memory");
    Q4_MFMA(0, 0);
    Q4_READ_B(1);
    asm volatile("s_waitcnt vmcnt(0)" ::: "memory");
    Q4_MFMA(0, 1);
    Q4_READ_A(1); Q4_READ_B(0);
    Q4_MFMA(1, 0);
    Q4_READ_B(1);
    Q4_MFMA(1, 1);
  }

  // epilogue: exp, E store, rowsum via 16-lane shfl + atomics
  u16* Eb = E + b * 4194304;
  float* lb = lsum + b * 2048;
#pragma unroll
  for (int ah = 0; ah < 2; ++ah)
#pragma unroll
    for (int mi = 0; mi < 4; ++mi) {
      floatx4 rs = {0.f, 0.f, 0.f, 0.f};
      const int rbase = m0 + ah * 128 + wr4 * 64 + mi * 16 + kq * 4;
#pragma unroll
      for (int bh = 0; bh < 2; ++bh)
#pragma unroll
        for (int ni = 0; ni < 2; ++ni) {
          const int n = n0 + bh * 128 + wc4 * 32 + ni * 16 + fr;
#pragma unroll
          for (int r = 0; r < 4; ++r) {
            const float e = __expf(acc[ah][bh][mi][ni][r]);
            rs[r] += e;
            Eb[(rbase + r) * 2048 + n] = f2bf(e);
          }
        }
#pragma unroll
      for (int off = 1; off < 16; off <<= 1) {
        rs[0] += __shfl_xor(rs[0], off, 64);
        rs[1] += __shfl_xor(rs[1], off, 64);
        rs[2] += __shfl_xor(rs[2], off, 64);
        rs[3] += __shfl_xor(rs[3], off, 64);
      }
      if (fr == 0) {
#pragma unroll
        for (int r = 0; r < 4; ++r) atomicAdd(&lb[rbase + r], rs[r]);
      }
    }
#undef Q4_READ_A
#undef Q4_READ_B
#undef Q4_MFMA
#undef ST_A
#undef ST_B
}

// ---------------------------------------------------------------------------
// K4: context = (E @ Vt) * (1/l) -> fp32 (R12 verbatim). grid (8,8,4) = 256.
__global__ __launch_bounds__(512, 2) void context_deep_kernel(
    const u16* __restrict__ E, const u16* __restrict__ vt,
    const float* __restrict__ lsum, float* __restrict__ out) {
  extern __shared__ __align__(16) u16 smem[];
  floatx4 acc[4][4];
#pragma unroll
  for (int i = 0; i < 4; ++i)
#pragma unroll
    for (int j = 0; j < 4; ++j) acc[i][j] = {0.f, 0.f, 0.f, 0.f};

  const int flat = blockIdx.x + blockIdx.y * 8 + blockIdx.z * 64;
  const int swz  = (flat & 7) * 32 + (flat >> 3);
  const int b    = swz >> 6;
  const int m0   = ((swz >> 3) & 7) * 256;
  const int n0   = (swz & 7) * 128;

  deep_core<32>(E + b * 4194304 + m0 * 2048, vt + b * 2097152 + n0 * 2048,
                2048, 2048, smem, acc);

  const int lane = threadIdx.x & 63, w = threadIdx.x >> 6;
  const int wm = w >> 1, wn = w & 1;
  const int fr = lane & 15, rg4 = (lane >> 4) * 4;
  const float* lb = lsum + b * 2048;

#pragma unroll
  for (int mi = 0; mi < 4; ++mi) {
    const int rbase = m0 + wm * 64 + mi * 16 + rg4;
    float rinv[4];
#pragma unroll
    for (int r = 0; r < 4; ++r) rinv[r] = 1.0f / lb[rbase + r];
#pragma unroll
    for (int ni = 0; ni < 4; ++ni) {
      const int n = n0 + wn * 64 + ni * 16 + fr;
#pragma unroll
      for (int r = 0; r < 4; ++r)
        out[(b * 2048 + rbase + r) * 1024 + n] = acc[mi][ni][r] * rinv[r];
    }
  }
}

// ---------------------------------------------------------------------------
// K3a: partial column sums (R12 verbatim). grid (4,32,2).
__global__ __launch_bounds__(256) void colsum_part_kernel(
    const u16* __restrict__ E, const float* __restrict__ lsum,
    float* __restrict__ part) {
  const int b  = blockIdx.x;
  const int g  = blockIdx.y;
  const int q0 = g * 64;
  const int j  = blockIdx.z * 1024 + threadIdx.x * 4;
  const u16* Eb = E + b * 4194304;
  const float* lb = lsum + b * 2048;
  float acc[4];
#pragma unroll
  for (int c = 0; c < 4; ++c) acc[c] = 0.f;
  for (int r = 0; r < 64; ++r) {
    const int qi = q0 + r;
    const float rinv = 1.0f / lb[qi];
    const ushort4v ev = *(const ushort4v*)(Eb + qi * 2048 + j);
#pragma unroll
    for (int c = 0; c < 4; ++c) acc[c] += bf2f((u16)ev[c]) * rinv;
  }
  float4 o = {acc[0], acc[1], acc[2], acc[3]};
  *(float4*)(part + (b * 32 + g) * 2048 + j) = o;
}

// K3b: scores[b][j] = sum_g part[b][g][j]
__global__ __launch_bounds__(256) void colsum_reduce_kernel(
    const float* __restrict__ part, float* __restrict__ scores) {
  const int b = blockIdx.x;
  const int j = blockIdx.y * 256 + threadIdx.x;
  const float* pb = part + b * 32 * 2048 + j;
  float s = 0.f;
#pragma unroll
  for (int g = 0; g < 32; ++g) s += pb[g * 2048];
  scores[b * 2048 + j] = s;
}

// ---------------------------------------------------------------------------
extern "C" void kernel_launch(void* const* d_in, const int* in_sizes, int n_in,
                              void* d_out, int out_size, void* d_ws, size_t ws_size,
                              hipStream_t stream) {
  const float* hs = (const float*)d_in[0];
  const float* Wq = (const float*)d_in[1];
  const float* bq = (const float*)d_in[2];
  const float* Wk = (const float*)d_in[3];
  const float* bk = (const float*)d_in[4];
  const float* Wv = (const float*)d_in[5];
  const float* bv = (const float*)d_in[6];

  char* ws = (char*)d_ws;
  u16*   qw  = (u16*)(ws);                                // 16 MB
  u16*   kw  = (u16*)(ws + (16u << 20));                  // 16 MB
  u16*   vtw = (u16*)(ws + (32u << 20));                  // 16 MB
  float* lw  = (float*)(ws + (48u << 20));                // 32 KB
  float* pw  = (float*)(ws + (48u << 20) + (128u << 10)); // 1 MB partials
  u16*   hsb = (u16*)(ws + (49u << 20));                  // 16 MB (dead after proj)
  u16*   Wb  = (u16*)(ws + (65u << 20));                  // 6 MB  (dead after proj)
  u16*   Ew  = (u16*)(ws + (49u << 20));                  // 32 MB (aliases hsb/Wb)

  float* outc = (float*)d_out;           // context [4,2048,1024]
  float* outs = outc + 8388608;          // scores  [4,2048]

  static int s_attr_done = 0;
  if (!s_attr_done) {
    (void)hipFuncSetAttribute((const void*)proj_deep_kernel,
                              hipFuncAttributeMaxDynamicSharedMemorySize, 147456);
    (void)hipFuncSetAttribute((const void*)logits_q4_kernel,
                              hipFuncAttributeMaxDynamicSharedMemorySize, 131072);
    (void)hipFuncSetAttribute((const void*)context_deep_kernel,
                              hipFuncAttributeMaxDynamicSharedMemorySize, 147456);
    s_attr_done = 1;
  }

  cvt_all_kernel<<<5632, 256, 0, stream>>>(hs, Wq, Wk, Wv, hsb, Wb, lw);
  proj_deep_kernel<<<dim3(8, 32, 3), 512, 147456, stream>>>(hsb, Wb, bq, bk, bv, qw, kw, vtw);
  logits_q4_kernel<<<dim3(8, 8, 4), 512, 131072, stream>>>(qw, kw, Ew, lw);
  context_deep_kernel<<<dim3(8, 8, 4), 512, 147456, stream>>>(Ew, vtw, lw, outc);
  colsum_part_kernel<<<dim3(4, 32, 2), 256, 0, stream>>>(Ew, lw, pw);
  colsum_reduce_kernel<<<dim3(4, 8), 256, 0, stream>>>(pw, outs);
}